// Round 1
// baseline (1409.019 us; speedup 1.0000x reference)
//
#include <hip/hip_runtime.h>

// DeepSeekV3 MoE: B=1 S=2048 H=2048, E=32 experts (4 groups), top-2 groups,
// top-4 experts, scale 2.5, I=1024. All inputs/outputs fp32; compute in bf16 MFMA.

#define T_TOK 2048
#define HD 2048
#define NE 32
#define NI 1024
#define NG 4
#define GSZ (NE / NG)   // 8 experts per group
#define SCALE_F 2.5f
#define HR_ROWS 10240   // sum of per-expert counts padded to 64 <= 8192 + 32*63

typedef unsigned short ushort_t;
typedef __attribute__((ext_vector_type(8))) short bf16x8;
typedef __attribute__((ext_vector_type(4))) float f32x4;

__device__ inline ushort_t f2bf(float f) {
  unsigned int x = __float_as_uint(f);
  unsigned int r = (x + 0x7fffu + ((x >> 16) & 1u)) >> 16;  // RNE
  return (ushort_t)r;
}

// ---- workspace layout (bytes) ----
#define XB_OFF   0ull                                 // ushort[T_TOK*HD]   8 MiB
#define CNT_OFF  (XB_OFF + 2ull * T_TOK * HD)         // int[NE]
#define OFFS_OFF (CNT_OFF + 256ull)                   // int[NE+1]
#define TOK_OFF  (OFFS_OFF + 256ull)                  // int[NE*T_TOK]
#define BW_OFF   (TOK_OFF + 4ull * NE * T_TOK)        // float[NE*T_TOK]
#define HR_OFF   (BW_OFF + 4ull * NE * T_TOK)         // ushort[HR_ROWS*NI] 20 MiB
#define HS_OFF   (HR_OFF + 2ull * HR_ROWS * NI)       // ushort[T_TOK*NI]    4 MiB
// total ~34 MiB

// ---- kernel 1: X fp32 -> bf16, zero out, zero counts ----
__global__ __launch_bounds__(256) void prep_kernel(const float* __restrict__ x,
    ushort_t* __restrict__ xb, float* __restrict__ out, int* __restrict__ counts) {
  if (blockIdx.x == 0 && threadIdx.x < NE) counts[threadIdx.x] = 0;
  int n4 = T_TOK * HD / 4;
  for (int i = blockIdx.x * blockDim.x + threadIdx.x; i < n4; i += gridDim.x * blockDim.x) {
    float4 v = ((const float4*)x)[i];
    uint2 p;
    p.x = (unsigned)f2bf(v.x) | ((unsigned)f2bf(v.y) << 16);
    p.y = (unsigned)f2bf(v.z) | ((unsigned)f2bf(v.w) << 16);
    ((uint2*)xb)[i] = p;
    ((float4*)out)[i] = make_float4(0.f, 0.f, 0.f, 0.f);
  }
}

// ---- kernel 2: gate + routing + bucket scatter (one wave per token) ----
__global__ __launch_bounds__(64) void gate_kernel(const float* __restrict__ x,
    const float* __restrict__ gw, const float* __restrict__ bias,
    int* __restrict__ counts, int* __restrict__ btok, float* __restrict__ bw) {
  int t = blockIdx.x;
  int lane = threadIdx.x;
  __shared__ float xs[HD];
  __shared__ float sc[NE];
  const float* xr = x + (size_t)t * HD;
  for (int j = lane; j < HD; j += 64) xs[j] = xr[j];
  __syncthreads();
  for (int e = 0; e < NE; e++) {
    const float* g = gw + (size_t)e * HD;
    float p = 0.f;
    for (int j = lane; j < HD; j += 64) p += xs[j] * g[j];
#pragma unroll
    for (int s = 32; s > 0; s >>= 1) p += __shfl_down(p, s);
    if (lane == 0) sc[e] = p;
  }
  __syncthreads();
  if (lane == 0) {
    float s[NE], sb[NE];
#pragma unroll
    for (int e = 0; e < NE; e++) {
      float sig = 1.f / (1.f + expf(-sc[e]));
      s[e] = sig;
      sb[e] = sig + bias[e];
    }
    // group score = sum of top-2 biased scores in group
    float gs[NG];
#pragma unroll
    for (int g = 0; g < NG; g++) {
      float m1 = -1e30f, m2 = -1e30f;
#pragma unroll
      for (int j = 0; j < GSZ; j++) {
        float v = sb[g * GSZ + j];
        if (v > m1) { m2 = m1; m1 = v; } else if (v > m2) { m2 = v; }
      }
      gs[g] = m1 + m2;
    }
    // top-2 groups (strict > keeps lowest index on ties, matching lax.top_k)
    int g0 = 0; float bv = -1e30f;
#pragma unroll
    for (int g = 0; g < NG; g++) if (gs[g] > bv) { bv = gs[g]; g0 = g; }
    int g1 = -1; bv = -1e30f;
#pragma unroll
    for (int g = 0; g < NG; g++) if (g != g0 && gs[g] > bv) { bv = gs[g]; g1 = g; }
    // top-4 experts among masked biased scores
    unsigned used = 0;
    int idx[4]; float sum = 0.f; float tw[4];
#pragma unroll
    for (int k = 0; k < 4; k++) {
      float best = -1e30f; int bi = 0;
#pragma unroll
      for (int e = 0; e < NE; e++) {
        int g = e >> 3;
        float v = (g == g0 || g == g1) ? sb[e] : 0.0f;
        if (!((used >> e) & 1u) && v > best) { best = v; bi = e; }
      }
      used |= 1u << bi;
      idx[k] = bi; tw[k] = s[bi]; sum += s[bi];
    }
    float inv = SCALE_F / (sum + 1e-20f);
    for (int k = 0; k < 4; k++) {
      int e = idx[k];
      int pos = atomicAdd(&counts[e], 1);
      btok[e * T_TOK + pos] = t;
      bw[e * T_TOK + pos] = tw[k] * inv;
    }
  }
}

// ---- kernel 3: padded prefix sums ----
__global__ void offsets_kernel(const int* __restrict__ counts, int* __restrict__ offs) {
  if (blockIdx.x == 0 && threadIdx.x == 0) {
    int o = 0;
    for (int e = 0; e < NE; e++) { offs[e] = o; o += (counts[e] + 63) & ~63; }
    offs[NE] = o;
  }
}

// ---- kernel 4: stage-1 grouped GEMM: h = silu(X w1^T) * (X w3^T), bf16 out ----
// grid: (NI/64, T_TOK/64, NE+1); z==NE -> shared expert
__global__ __launch_bounds__(256) void stage1_kernel(
    const float* __restrict__ w1, const float* __restrict__ w3,
    const float* __restrict__ ws1, const float* __restrict__ ws3,
    const ushort_t* __restrict__ xb, const int* __restrict__ counts,
    const int* __restrict__ offs, const int* __restrict__ btok,
    ushort_t* __restrict__ hr, ushort_t* __restrict__ hs) {
  int e = blockIdx.z, mt = blockIdx.y, nt = blockIdx.x;
  int cnt, base;
  const float *W1, *W3;
  ushort_t* ho;
  const int* tok = nullptr;
  if (e == NE) {
    cnt = T_TOK; W1 = ws1; W3 = ws3; ho = hs; base = 0;
  } else {
    cnt = counts[e];
    if (mt * 64 >= cnt) return;
    W1 = w1 + (size_t)e * NI * HD;
    W3 = w3 + (size_t)e * NI * HD;
    ho = hr; base = offs[e];
    tok = btok + (size_t)e * T_TOK;
  }
  __shared__ __align__(16) ushort_t As[64 * 40];
  __shared__ __align__(16) ushort_t B1s[64 * 40];
  __shared__ __align__(16) ushort_t B3s[64 * 40];
  __shared__ int toks[64];
  int tid = threadIdx.x;
  if (tid < 64) {
    int m = mt * 64 + tid;
    toks[tid] = (e == NE) ? m : tok[min(m, cnt - 1)];
  }
  __syncthreads();

  int row = tid >> 2, q = tid & 3;              // staging: row 0..63, quad 0..3
  int wave = tid >> 6, lane = tid & 63;
  int lm = lane & 15, lq = lane >> 4;           // mfma lane decomposition
  int nbase = nt * 64;
  f32x4 acc1[4], acc3[4];
#pragma unroll
  for (int i = 0; i < 4; i++) { acc1[i] = (f32x4){0.f,0.f,0.f,0.f}; acc3[i] = (f32x4){0.f,0.f,0.f,0.f}; }

  size_t arow = (size_t)toks[row] * HD;
  for (int kb = 0; kb < HD / 32; kb++) {
    int k0 = kb * 32;
    // A: 64x32 bf16 (gathered token rows)
    *(uint4*)(As + row * 40 + q * 8) = *(const uint4*)(xb + arow + k0 + q * 8);
    // B1/B3: 64x32 fp32 -> bf16
    {
      const float* s1 = W1 + (size_t)(nbase + row) * HD + k0 + q * 8;
      float4 a0 = ((const float4*)s1)[0], a1 = ((const float4*)s1)[1];
      uint4 v;
      v.x = (unsigned)f2bf(a0.x) | ((unsigned)f2bf(a0.y) << 16);
      v.y = (unsigned)f2bf(a0.z) | ((unsigned)f2bf(a0.w) << 16);
      v.z = (unsigned)f2bf(a1.x) | ((unsigned)f2bf(a1.y) << 16);
      v.w = (unsigned)f2bf(a1.z) | ((unsigned)f2bf(a1.w) << 16);
      *(uint4*)(B1s + row * 40 + q * 8) = v;
    }
    {
      const float* s3 = W3 + (size_t)(nbase + row) * HD + k0 + q * 8;
      float4 a0 = ((const float4*)s3)[0], a1 = ((const float4*)s3)[1];
      uint4 v;
      v.x = (unsigned)f2bf(a0.x) | ((unsigned)f2bf(a0.y) << 16);
      v.y = (unsigned)f2bf(a0.z) | ((unsigned)f2bf(a0.w) << 16);
      v.z = (unsigned)f2bf(a1.x) | ((unsigned)f2bf(a1.y) << 16);
      v.w = (unsigned)f2bf(a1.z) | ((unsigned)f2bf(a1.w) << 16);
      *(uint4*)(B3s + row * 40 + q * 8) = v;
    }
    __syncthreads();
    bf16x8 af = *(const bf16x8*)(As + (wave * 16 + lm) * 40 + lq * 8);
#pragma unroll
    for (int n4 = 0; n4 < 4; n4++) {
      bf16x8 b1 = *(const bf16x8*)(B1s + (n4 * 16 + lm) * 40 + lq * 8);
      bf16x8 b3 = *(const bf16x8*)(B3s + (n4 * 16 + lm) * 40 + lq * 8);
      acc1[n4] = __builtin_amdgcn_mfma_f32_16x16x32_bf16(af, b1, acc1[n4], 0, 0, 0);
      acc3[n4] = __builtin_amdgcn_mfma_f32_16x16x32_bf16(af, b3, acc3[n4], 0, 0, 0);
    }
    __syncthreads();
  }
  // epilogue: h = silu(acc1) * acc3  (C/D layout: col=lane&15, row=lq*4+reg)
#pragma unroll
  for (int n4 = 0; n4 < 4; n4++) {
#pragma unroll
    for (int r = 0; r < 4; r++) {
      float g = acc1[n4][r], u = acc3[n4][r];
      float hv = (g / (1.f + __expf(-g))) * u;
      int rrow = wave * 16 + lq * 4 + r;
      int col = nbase + n4 * 16 + lm;
      ho[(size_t)(base + mt * 64 + rrow) * NI + col] = f2bf(hv);
    }
  }
}

// ---- kernel 5: stage-2 grouped GEMM: out += weight * (h w2^T), atomic ----
// grid: (HD/64, T_TOK/64, NE+1); z==NE -> shared expert (weight 1)
__global__ __launch_bounds__(256) void stage2_kernel(
    const float* __restrict__ w2, const float* __restrict__ ws2,
    const ushort_t* __restrict__ hr, const ushort_t* __restrict__ hs,
    const int* __restrict__ counts, const int* __restrict__ offs,
    const int* __restrict__ btok, const float* __restrict__ bw,
    float* __restrict__ out) {
  int e = blockIdx.z, mt = blockIdx.y, nt = blockIdx.x;
  int cnt, base;
  const float* W2;
  const ushort_t* hsrc;
  if (e == NE) {
    cnt = T_TOK; W2 = ws2; hsrc = hs; base = 0;
  } else {
    cnt = counts[e];
    if (mt * 64 >= cnt) return;
    W2 = w2 + (size_t)e * HD * NI;
    hsrc = hr; base = offs[e];
  }
  __shared__ __align__(16) ushort_t As[64 * 40];
  __shared__ __align__(16) ushort_t Bs[64 * 40];
  __shared__ int toks[64];
  __shared__ float wts[64];
  int tid = threadIdx.x;
  if (tid < 64) {
    int m = mt * 64 + tid;
    if (e == NE) { toks[tid] = m; wts[tid] = 1.f; }
    else {
      int mm = min(m, cnt - 1);
      toks[tid] = btok[(size_t)e * T_TOK + mm];
      wts[tid] = bw[(size_t)e * T_TOK + mm];
    }
  }
  int row = tid >> 2, q = tid & 3;
  int wave = tid >> 6, lane = tid & 63;
  int lm = lane & 15, lq = lane >> 4;
  int nbase = nt * 64;
  f32x4 acc[4];
#pragma unroll
  for (int i = 0; i < 4; i++) acc[i] = (f32x4){0.f,0.f,0.f,0.f};

  size_t hrow = (size_t)(base + mt * 64 + row) * NI;
  for (int kb = 0; kb < NI / 32; kb++) {
    int k0 = kb * 32;
    *(uint4*)(As + row * 40 + q * 8) = *(const uint4*)(hsrc + hrow + k0 + q * 8);
    {
      const float* s2 = W2 + (size_t)(nbase + row) * NI + k0 + q * 8;
      float4 a0 = ((const float4*)s2)[0], a1 = ((const float4*)s2)[1];
      uint4 v;
      v.x = (unsigned)f2bf(a0.x) | ((unsigned)f2bf(a0.y) << 16);
      v.y = (unsigned)f2bf(a0.z) | ((unsigned)f2bf(a0.w) << 16);
      v.z = (unsigned)f2bf(a1.x) | ((unsigned)f2bf(a1.y) << 16);
      v.w = (unsigned)f2bf(a1.z) | ((unsigned)f2bf(a1.w) << 16);
      *(uint4*)(Bs + row * 40 + q * 8) = v;
    }
    __syncthreads();
    bf16x8 af = *(const bf16x8*)(As + (wave * 16 + lm) * 40 + lq * 8);
#pragma unroll
    for (int n4 = 0; n4 < 4; n4++) {
      bf16x8 b = *(const bf16x8*)(Bs + (n4 * 16 + lm) * 40 + lq * 8);
      acc[n4] = __builtin_amdgcn_mfma_f32_16x16x32_bf16(af, b, acc[n4], 0, 0, 0);
    }
    __syncthreads();
  }
#pragma unroll
  for (int n4 = 0; n4 < 4; n4++) {
#pragma unroll
    for (int r = 0; r < 4; r++) {
      int m = wave * 16 + lq * 4 + r;
      if (mt * 64 + m < cnt) {
        float v = acc[n4][r] * wts[m];
        atomicAdd(out + (size_t)toks[m] * HD + nbase + n4 * 16 + lm, v);
      }
    }
  }
}

extern "C" void kernel_launch(void* const* d_in, const int* in_sizes, int n_in,
                              void* d_out, int out_size, void* d_ws, size_t ws_size,
                              hipStream_t stream) {
  const float* x    = (const float*)d_in[0];
  const float* gw   = (const float*)d_in[1];
  const float* bias = (const float*)d_in[2];
  const float* w1   = (const float*)d_in[3];
  const float* w3   = (const float*)d_in[4];
  const float* w2   = (const float*)d_in[5];
  const float* ws1  = (const float*)d_in[6];
  const float* ws3  = (const float*)d_in[7];
  const float* ws2  = (const float*)d_in[8];
  float* out = (float*)d_out;
  char* ws = (char*)d_ws;

  ushort_t* xb  = (ushort_t*)(ws + XB_OFF);
  int* counts   = (int*)(ws + CNT_OFF);
  int* offs     = (int*)(ws + OFFS_OFF);
  int* btok     = (int*)(ws + TOK_OFF);
  float* bwts   = (float*)(ws + BW_OFF);
  ushort_t* hr  = (ushort_t*)(ws + HR_OFF);
  ushort_t* hs  = (ushort_t*)(ws + HS_OFF);

  prep_kernel<<<1024, 256, 0, stream>>>(x, xb, out, counts);
  gate_kernel<<<T_TOK, 64, 0, stream>>>(x, gw, bias, counts, btok, bwts);
  offsets_kernel<<<1, 64, 0, stream>>>(counts, offs);
  stage1_kernel<<<dim3(NI / 64, T_TOK / 64, NE + 1), 256, 0, stream>>>(
      w1, w3, ws1, ws3, xb, counts, offs, btok, hr, hs);
  stage2_kernel<<<dim3(HD / 64, T_TOK / 64, NE + 1), 256, 0, stream>>>(
      w2, ws2, hr, hs, counts, offs, btok, bwts, out);
}

// Round 2
// 1015.811 us; speedup vs baseline: 1.3871x; 1.3871x over previous
//
#include <hip/hip_runtime.h>

// DeepSeekV3 MoE: B=1 S=2048 H=2048, E=32 (4 groups, top-2 groups, top-4),
// scale 2.5, I=1024 (+shared expert I=1024). fp32 in/out; bf16 MFMA compute.

#define T_TOK 2048
#define HD 2048
#define NE 32
#define NI 1024
#define NG 4
#define GSZ (NE / NG)
#define SCALE_F 2.5f

typedef unsigned short ushort_t;
typedef __attribute__((ext_vector_type(8))) short bf16x8;
typedef __attribute__((ext_vector_type(4))) float f32x4;

__device__ inline ushort_t f2bf(float f) {
  unsigned int x = __float_as_uint(f);
  unsigned int r = (x + 0x7fffu + ((x >> 16) & 1u)) >> 16;  // RNE
  return (ushort_t)r;
}
__device__ inline unsigned pack2(float a, float b) {
  return (unsigned)f2bf(a) | ((unsigned)f2bf(b) << 16);
}

#define GLDS(gp, lp) \
  __builtin_amdgcn_global_load_lds((const __attribute__((address_space(1))) void*)(gp), \
                                   (__attribute__((address_space(3))) void*)(lp), 16, 0, 0)

// ---- workspace layout (bytes) ----
#define XB_OFF   0ull                                 // ushort[T*H]       8 MiB
#define CNT_OFF  (XB_OFF + 2ull * T_TOK * HD)         // int[NE]
#define OFFS_OFF (CNT_OFF + 256ull)                   // int[NE+1]
#define TOK_OFF  (OFFS_OFF + 256ull)                  // int[NE*T]
#define BW_OFF   (TOK_OFF + 4ull * NE * T_TOK)        // float[NE*T]
#define SC_OFF   (BW_OFF + 4ull * NE * T_TOK)         // float[T*NE]
#define HR_ROWS  12288                                // sum cnt padded to 128
#define HR_OFF   (SC_OFF + 4ull * T_TOK * NE)         // ushort[HR_ROWS*NI] 24 MiB
#define HS_OFF   (HR_OFF + 2ull * HR_ROWS * NI)       // ushort[T*NI]        4 MiB

// ---- kernel 1: X fp32 -> bf16, zero out, zero counts ----
__global__ __launch_bounds__(256) void prep_kernel(const float* __restrict__ x,
    ushort_t* __restrict__ xb, float* __restrict__ out, int* __restrict__ counts) {
  if (blockIdx.x == 0 && threadIdx.x < NE) counts[threadIdx.x] = 0;
  int n4 = T_TOK * HD / 4;
  for (int i = blockIdx.x * blockDim.x + threadIdx.x; i < n4; i += gridDim.x * blockDim.x) {
    float4 v = ((const float4*)x)[i];
    uint2 p;
    p.x = pack2(v.x, v.y);
    p.y = pack2(v.z, v.w);
    ((uint2*)xb)[i] = p;
    ((float4*)out)[i] = make_float4(0.f, 0.f, 0.f, 0.f);
  }
}

// ---- kernel 2a: logits = X @ gw^T (fp32, tiled LDS GEMM) ----
// grid 256 blocks x 256 thr; 8 tokens/block; thread owns (tok, expert) pair
__global__ __launch_bounds__(256) void logits_kernel(const float* __restrict__ x,
    const float* __restrict__ gw, float* __restrict__ scores) {
  __shared__ float4 gws[32 * 65];   // 32 experts x 64 float4, pad +1 (bank spread)
  __shared__ float4 xs[8 * 64];
  int tid = threadIdx.x;
  int t0 = blockIdx.x * 8;
  const float4* x4 = (const float4*)x;
  const float4* g4 = (const float4*)gw;
  int tok = tid >> 5, e = tid & 31;
  float acc = 0.f;
  for (int c = 0; c < 8; c++) {       // K chunks of 256 floats
    int k4 = c * 64;
    for (int j = tid; j < 32 * 64; j += 256)
      gws[(j >> 6) * 65 + (j & 63)] = g4[(size_t)(j >> 6) * (HD / 4) + k4 + (j & 63)];
    for (int j = tid; j < 8 * 64; j += 256)
      xs[j] = x4[(size_t)(t0 + (j >> 6)) * (HD / 4) + k4 + (j & 63)];
    __syncthreads();
#pragma unroll 8
    for (int c4 = 0; c4 < 64; c4++) {
      float4 xv = xs[tok * 64 + c4];
      float4 wv = gws[e * 65 + c4];
      acc += xv.x * wv.x + xv.y * wv.y + xv.z * wv.z + xv.w * wv.w;
    }
    __syncthreads();
  }
  scores[(size_t)(t0 + tok) * NE + e] = acc;
}

// ---- kernel 2b: routing (one thread per token) ----
__global__ __launch_bounds__(256) void route_kernel(const float* __restrict__ scores,
    const float* __restrict__ bias, int* __restrict__ counts,
    int* __restrict__ btok, float* __restrict__ bw) {
  int t = blockIdx.x * 256 + threadIdx.x;
  if (t >= T_TOK) return;
  float s[NE], sb[NE];
#pragma unroll
  for (int e = 0; e < NE; e++) {
    float sig = 1.f / (1.f + expf(-scores[(size_t)t * NE + e]));
    s[e] = sig;
    sb[e] = sig + bias[e];
  }
  float gs[NG];
#pragma unroll
  for (int g = 0; g < NG; g++) {
    float m1 = -1e30f, m2 = -1e30f;
#pragma unroll
    for (int j = 0; j < GSZ; j++) {
      float v = sb[g * GSZ + j];
      if (v > m1) { m2 = m1; m1 = v; } else if (v > m2) { m2 = v; }
    }
    gs[g] = m1 + m2;
  }
  int g0 = 0; float bv = -1e30f;
#pragma unroll
  for (int g = 0; g < NG; g++) if (gs[g] > bv) { bv = gs[g]; g0 = g; }
  int g1 = -1; bv = -1e30f;
#pragma unroll
  for (int g = 0; g < NG; g++) if (g != g0 && gs[g] > bv) { bv = gs[g]; g1 = g; }
  unsigned used = 0;
  int idx[4]; float tw[4]; float sum = 0.f;
#pragma unroll
  for (int k = 0; k < 4; k++) {
    float best = -1e30f; int bi = 0;
#pragma unroll
    for (int e = 0; e < NE; e++) {
      int g = e >> 3;
      float v = (g == g0 || g == g1) ? sb[e] : 0.0f;
      if (!((used >> e) & 1u) && v > best) { best = v; bi = e; }
    }
    used |= 1u << bi;
    idx[k] = bi; tw[k] = s[bi]; sum += s[bi];
  }
  float inv = SCALE_F / (sum + 1e-20f);
#pragma unroll
  for (int k = 0; k < 4; k++) {
    int e = idx[k];
    int pos = atomicAdd(&counts[e], 1);
    btok[(size_t)e * T_TOK + pos] = t;
    bw[(size_t)e * T_TOK + pos] = tw[k] * inv;
  }
}

// ---- kernel 3: padded prefix sums (pad 128) ----
__global__ void offsets_kernel(const int* __restrict__ counts, int* __restrict__ offs) {
  if (blockIdx.x == 0 && threadIdx.x == 0) {
    int o = 0;
    for (int e = 0; e < NE; e++) { offs[e] = o; o += (counts[e] + 127) & ~127; }
    offs[NE] = o;
  }
}

// ---- kernel 4: stage-1: h = silu(X w1^T) * (X w3^T), 128x64 tile, bf16 out ----
// grid (NI/64, T/128, NE+1); z==NE -> shared expert
__global__ __launch_bounds__(256) void stage1_kernel(
    const float* __restrict__ w1, const float* __restrict__ w3,
    const float* __restrict__ ws1f, const float* __restrict__ ws3f,
    const ushort_t* __restrict__ xb, const int* __restrict__ counts,
    const int* __restrict__ offs, const int* __restrict__ btok,
    ushort_t* __restrict__ hr, ushort_t* __restrict__ hs) {
  int e = blockIdx.z, mt = blockIdx.y, nt = blockIdx.x;
  int cnt, base;
  const float *W1, *W3;
  ushort_t* ho;
  if (e == NE) {
    cnt = T_TOK; W1 = ws1f; W3 = ws3f; ho = hs; base = 0;
  } else {
    cnt = counts[e];
    if (mt * 128 >= cnt) return;
    W1 = w1 + (size_t)e * NI * HD;
    W3 = w3 + (size_t)e * NI * HD;
    ho = hr; base = offs[e];
  }
  __shared__ __align__(16) ushort_t As[128 * 32];   // no pad: global_load_lds layout
  __shared__ __align__(16) ushort_t B1s[64 * 40];   // pad 40
  __shared__ __align__(16) ushort_t B3s[64 * 40];
  __shared__ int toks[128];
  int tid = threadIdx.x, wave = tid >> 6, lane = tid & 63;
  if (tid < 128) {
    int m = mt * 128 + tid;
    toks[tid] = (e == NE) ? min(m, T_TOK - 1) : btok[(size_t)e * T_TOK + min(m, cnt - 1)];
  }
  __syncthreads();
  int lm = lane & 15, lq = lane >> 4;
  int nbase = nt * 64;
  // A staging: round r covers rows r*64 + wave*16 + lane/4, 8 bf16 per lane
  int ar = wave * 16 + (lane >> 2);
  int acol = (lane & 3) * 8;
  const ushort_t* ag0 = xb + (size_t)toks[ar] * HD + acol;
  const ushort_t* ag1 = xb + (size_t)toks[64 + ar] * HD + acol;
  ushort_t* al0 = As + wave * 512 + lane * 8;
  ushort_t* al1 = As + 2048 + wave * 512 + lane * 8;
  // B staging (fp32 -> bf16 inline): thread owns row tid/4, 8 cols
  int br = tid >> 2, bc = (tid & 3) * 8;
  const float* b1g = W1 + (size_t)(nbase + br) * HD + bc;
  const float* b3g = W3 + (size_t)(nbase + br) * HD + bc;
  ushort_t* b1l = B1s + br * 40 + bc;
  ushort_t* b3l = B3s + br * 40 + bc;

  f32x4 acc1[2][4], acc3[2][4];
#pragma unroll
  for (int i = 0; i < 2; i++)
#pragma unroll
    for (int j = 0; j < 4; j++) {
      acc1[i][j] = (f32x4){0.f, 0.f, 0.f, 0.f};
      acc3[i][j] = (f32x4){0.f, 0.f, 0.f, 0.f};
    }

  for (int kb = 0; kb < HD / 32; kb++) {
    int k0 = kb * 32;
    GLDS(ag0 + k0, al0);
    GLDS(ag1 + k0, al1);
    {
      float4 v0 = *(const float4*)(b1g + k0);
      float4 v1 = *(const float4*)(b1g + k0 + 4);
      uint4 p;
      p.x = pack2(v0.x, v0.y); p.y = pack2(v0.z, v0.w);
      p.z = pack2(v1.x, v1.y); p.w = pack2(v1.z, v1.w);
      *(uint4*)b1l = p;
    }
    {
      float4 v0 = *(const float4*)(b3g + k0);
      float4 v1 = *(const float4*)(b3g + k0 + 4);
      uint4 p;
      p.x = pack2(v0.x, v0.y); p.y = pack2(v0.z, v0.w);
      p.z = pack2(v1.x, v1.y); p.w = pack2(v1.z, v1.w);
      *(uint4*)b3l = p;
    }
    __syncthreads();
    bf16x8 a0 = *(const bf16x8*)(As + (wave * 32 + lm) * 32 + lq * 8);
    bf16x8 a1 = *(const bf16x8*)(As + (wave * 32 + 16 + lm) * 32 + lq * 8);
#pragma unroll
    for (int n4 = 0; n4 < 4; n4++) {
      bf16x8 b1 = *(const bf16x8*)(B1s + (n4 * 16 + lm) * 40 + lq * 8);
      bf16x8 b3 = *(const bf16x8*)(B3s + (n4 * 16 + lm) * 40 + lq * 8);
      acc1[0][n4] = __builtin_amdgcn_mfma_f32_16x16x32_bf16(a0, b1, acc1[0][n4], 0, 0, 0);
      acc1[1][n4] = __builtin_amdgcn_mfma_f32_16x16x32_bf16(a1, b1, acc1[1][n4], 0, 0, 0);
      acc3[0][n4] = __builtin_amdgcn_mfma_f32_16x16x32_bf16(a0, b3, acc3[0][n4], 0, 0, 0);
      acc3[1][n4] = __builtin_amdgcn_mfma_f32_16x16x32_bf16(a1, b3, acc3[1][n4], 0, 0, 0);
    }
    __syncthreads();
  }
  // epilogue: silu(g)*u; C/D layout col=lane&15, row=lq*4+r
#pragma unroll
  for (int i = 0; i < 2; i++)
#pragma unroll
    for (int n4 = 0; n4 < 4; n4++)
#pragma unroll
      for (int r = 0; r < 4; r++) {
        int row = wave * 32 + i * 16 + lq * 4 + r;
        float g = acc1[i][n4][r], u = acc3[i][n4][r];
        float hv = (g / (1.f + __expf(-g))) * u;
        ho[(size_t)(base + mt * 128 + row) * NI + nbase + n4 * 16 + lm] = f2bf(hv);
      }
}

// ---- kernel 5: stage-2: out += w * (h w2^T), 128x128 tile, atomic ----
// grid (HD/128, T/128, NE+1)
__global__ __launch_bounds__(256) void stage2_kernel(
    const float* __restrict__ w2, const float* __restrict__ ws2f,
    const ushort_t* __restrict__ hr, const ushort_t* __restrict__ hs,
    const int* __restrict__ counts, const int* __restrict__ offs,
    const int* __restrict__ btok, const float* __restrict__ bw,
    float* __restrict__ out) {
  int e = blockIdx.z, mt = blockIdx.y, nt = blockIdx.x;
  int cnt, base;
  const float* W2;
  const ushort_t* hsrc;
  if (e == NE) {
    cnt = T_TOK; W2 = ws2f; hsrc = hs; base = 0;
  } else {
    cnt = counts[e];
    if (mt * 128 >= cnt) return;
    W2 = w2 + (size_t)e * HD * NI;
    hsrc = hr; base = offs[e];
  }
  __shared__ __align__(16) ushort_t As[128 * 32];
  __shared__ __align__(16) ushort_t Bs[128 * 40];
  __shared__ int toks[128];
  __shared__ float wts[128];
  int tid = threadIdx.x, wave = tid >> 6, lane = tid & 63;
  if (tid < 128) {
    int m = mt * 128 + tid;
    if (e == NE) { toks[tid] = m; wts[tid] = 1.f; }
    else {
      int mm = min(m, cnt - 1);
      toks[tid] = btok[(size_t)e * T_TOK + mm];
      wts[tid] = bw[(size_t)e * T_TOK + mm];
    }
  }
  __syncthreads();
  int lm = lane & 15, lq = lane >> 4;
  int wr = wave >> 1, wc = wave & 1;
  // A staging: contiguous compacted rows
  const ushort_t* ag = hsrc + (size_t)(base + mt * 128) * NI;
  int ar = wave * 16 + (lane >> 2);
  int acol = (lane & 3) * 8;
  const ushort_t* ag0 = ag + (size_t)ar * NI + acol;
  const ushort_t* ag1 = ag + (size_t)(64 + ar) * NI + acol;
  ushort_t* al0 = As + wave * 512 + lane * 8;
  ushort_t* al1 = As + 2048 + wave * 512 + lane * 8;
  // B staging (fp32 -> bf16): thread owns rows br, br+64
  int br = tid >> 2, bc = (tid & 3) * 8;
  const float* bg0 = W2 + (size_t)(nt * 128 + br) * NI + bc;
  const float* bg1 = W2 + (size_t)(nt * 128 + 64 + br) * NI + bc;
  ushort_t* bl0 = Bs + br * 40 + bc;
  ushort_t* bl1 = Bs + (64 + br) * 40 + bc;

  f32x4 acc[4][4];
#pragma unroll
  for (int i = 0; i < 4; i++)
#pragma unroll
    for (int j = 0; j < 4; j++) acc[i][j] = (f32x4){0.f, 0.f, 0.f, 0.f};

  for (int kb = 0; kb < NI / 32; kb++) {
    int k0 = kb * 32;
    GLDS(ag0 + k0, al0);
    GLDS(ag1 + k0, al1);
    {
      float4 v0 = *(const float4*)(bg0 + k0);
      float4 v1 = *(const float4*)(bg0 + k0 + 4);
      uint4 p;
      p.x = pack2(v0.x, v0.y); p.y = pack2(v0.z, v0.w);
      p.z = pack2(v1.x, v1.y); p.w = pack2(v1.z, v1.w);
      *(uint4*)bl0 = p;
    }
    {
      float4 v0 = *(const float4*)(bg1 + k0);
      float4 v1 = *(const float4*)(bg1 + k0 + 4);
      uint4 p;
      p.x = pack2(v0.x, v0.y); p.y = pack2(v0.z, v0.w);
      p.z = pack2(v1.x, v1.y); p.w = pack2(v1.z, v1.w);
      *(uint4*)bl1 = p;
    }
    __syncthreads();
    bf16x8 a[4], b[4];
#pragma unroll
    for (int i = 0; i < 4; i++)
      a[i] = *(const bf16x8*)(As + (wr * 64 + i * 16 + lm) * 32 + lq * 8);
#pragma unroll
    for (int j = 0; j < 4; j++)
      b[j] = *(const bf16x8*)(Bs + (wc * 64 + j * 16 + lm) * 40 + lq * 8);
#pragma unroll
    for (int i = 0; i < 4; i++)
#pragma unroll
      for (int j = 0; j < 4; j++)
        acc[i][j] = __builtin_amdgcn_mfma_f32_16x16x32_bf16(a[i], b[j], acc[i][j], 0, 0, 0);
    __syncthreads();
  }
#pragma unroll
  for (int i = 0; i < 4; i++)
#pragma unroll
    for (int j = 0; j < 4; j++)
#pragma unroll
      for (int r = 0; r < 4; r++) {
        int m = wr * 64 + i * 16 + lq * 4 + r;
        if (mt * 128 + m < cnt) {
          float v = acc[i][j][r] * wts[m];
          atomicAdd(out + (size_t)toks[m] * HD + nt * 128 + wc * 64 + j * 16 + lm, v);
        }
      }
}

extern "C" void kernel_launch(void* const* d_in, const int* in_sizes, int n_in,
                              void* d_out, int out_size, void* d_ws, size_t ws_size,
                              hipStream_t stream) {
  const float* x    = (const float*)d_in[0];
  const float* gw   = (const float*)d_in[1];
  const float* bias = (const float*)d_in[2];
  const float* w1   = (const float*)d_in[3];
  const float* w3   = (const float*)d_in[4];
  const float* w2   = (const float*)d_in[5];
  const float* ws1  = (const float*)d_in[6];
  const float* ws3  = (const float*)d_in[7];
  const float* ws2  = (const float*)d_in[8];
  float* out = (float*)d_out;
  char* ws = (char*)d_ws;

  ushort_t* xb  = (ushort_t*)(ws + XB_OFF);
  int* counts   = (int*)(ws + CNT_OFF);
  int* offs     = (int*)(ws + OFFS_OFF);
  int* btok     = (int*)(ws + TOK_OFF);
  float* bwts   = (float*)(ws + BW_OFF);
  float* scores = (float*)(ws + SC_OFF);
  ushort_t* hr  = (ushort_t*)(ws + HR_OFF);
  ushort_t* hs  = (ushort_t*)(ws + HS_OFF);

  prep_kernel<<<1024, 256, 0, stream>>>(x, xb, out, counts);
  logits_kernel<<<T_TOK / 8, 256, 0, stream>>>(x, gw, scores);
  route_kernel<<<T_TOK / 256, 256, 0, stream>>>(scores, bias, counts, btok, bwts);
  offsets_kernel<<<1, 64, 0, stream>>>(counts, offs);
  stage1_kernel<<<dim3(NI / 64, T_TOK / 128, NE + 1), 256, 0, stream>>>(
      w1, w3, ws1, ws3, xb, counts, offs, btok, hr, hs);
  stage2_kernel<<<dim3(HD / 128, T_TOK / 128, NE + 1), 256, 0, stream>>>(
      w2, ws2, hr, hs, counts, offs, btok, bwts, out);
}